// Round 1
// baseline (1584.823 us; speedup 1.0000x reference)
//
#include <hip/hip_runtime.h>
#include <hip/hip_bf16.h>

#define NUM_USER   50000
#define NUM_ITEM   50000
#define NUM_NODES  100000
#define DIM_LATENT 256
#define DIM_ID     64
#define NUM_EDGES  2000000

static __device__ __forceinline__ float lrelu(float x) {
    return x > 0.0f ? x : 0.01f * x;
}

// ---------------- degree ----------------
__global__ void k_deg(const int* __restrict__ row, float* __restrict__ deg) {
    int t = blockIdx.x * blockDim.x + threadIdx.x;
    if (t < NUM_EDGES) atomicAdd(&deg[row[t]], 1.0f);
}

// ---------------- per-edge norm ----------------
__global__ void k_norm(const int* __restrict__ row, const int* __restrict__ col,
                       const float* __restrict__ deg, float* __restrict__ norm) {
    int t = blockIdx.x * blockDim.x + threadIdx.x;
    if (t < NUM_EDGES) {
        float dr = rsqrtf(fmaxf(deg[row[t]], 1.0f));
        float dc = rsqrtf(fmaxf(deg[col[t]], 1.0f));
        norm[t] = dr * dc;
    }
}

// ---------------- layer 1: normalize x row + x@W_gcn0 and lrelu(x@lin_w0+b)+id ----------------
// one wave per node row; 4 rows per 256-thread block; NUM_NODES % 4 == 0
__global__ void __launch_bounds__(256) k_layer1(
    const float* __restrict__ pref, const float* __restrict__ feat,
    const float* __restrict__ Wg,   const float* __restrict__ Wl,
    const float* __restrict__ lb,   const float* __restrict__ idemb,
    float* __restrict__ h, float* __restrict__ xhat)
{
    __shared__ float xs[4][DIM_LATENT];
    const int wave = threadIdx.x >> 6;
    const int lane = threadIdx.x & 63;
    const int n = blockIdx.x * 4 + wave;

    const float* src = (n < NUM_USER) ? (pref + (size_t)n * DIM_LATENT)
                                      : (feat + (size_t)(n - NUM_USER) * DIM_LATENT);
    float4 v = reinterpret_cast<const float4*>(src)[lane];
    float ss = v.x * v.x + v.y * v.y + v.z * v.z + v.w * v.w;
    #pragma unroll
    for (int off = 32; off >= 1; off >>= 1) ss += __shfl_xor(ss, off);
    float scale = 1.0f / fmaxf(sqrtf(ss), 1e-12f);
    xs[wave][lane * 4 + 0] = v.x * scale;
    xs[wave][lane * 4 + 1] = v.y * scale;
    xs[wave][lane * 4 + 2] = v.z * scale;
    xs[wave][lane * 4 + 3] = v.w * scale;
    __syncthreads();

    const float* xr = xs[wave];
    float a0 = 0.0f, a1 = 0.0f;
    #pragma unroll 8
    for (int k = 0; k < DIM_LATENT; ++k) {
        float xk = xr[k];
        a0 += xk * Wg[k * DIM_ID + lane];
        a1 += xk * Wl[k * DIM_ID + lane];
    }
    h[(size_t)n * DIM_ID + lane] = a0;
    float xh = lrelu(a1 + lb[lane]);
    xhat[(size_t)n * DIM_ID + lane] = xh + idemb[(size_t)n * DIM_ID + lane];
}

// ---------------- scatter-add messages: H[row] += h[col] * norm ----------------
__global__ void k_scatter(const float* __restrict__ h, const float* __restrict__ norm,
                          const int* __restrict__ row, const int* __restrict__ col,
                          float* __restrict__ H)
{
    const long long total = (long long)NUM_EDGES * DIM_ID;
    const long long stride = (long long)gridDim.x * blockDim.x;
    for (long long t = (long long)blockIdx.x * blockDim.x + threadIdx.x; t < total; t += stride) {
        int e = (int)(t >> 6);
        int d = (int)(t & 63);
        int r = row[e], c = col[e];
        float val = h[(size_t)c * DIM_ID + d] * norm[e];
        atomicAdd(&H[(size_t)r * DIM_ID + d], val);
    }
}

// ---------------- combine: out = lrelu( lrelu(H) @ g_w + g_b + xhat ) ----------------
__global__ void __launch_bounds__(256) k_combine(
    const float* __restrict__ H, const float* __restrict__ xhat,
    const float* __restrict__ gw, const float* __restrict__ gb,
    float* __restrict__ out)
{
    const int wave = threadIdx.x >> 6;
    const int lane = threadIdx.x & 63;
    const int n = blockIdx.x * 4 + wave;

    float hv = lrelu(H[(size_t)n * DIM_ID + lane]);
    float acc = 0.0f;
    #pragma unroll
    for (int k = 0; k < DIM_ID; ++k) {
        float b = __shfl(hv, k);
        acc += b * gw[k * DIM_ID + lane];
    }
    acc += gb[lane] + xhat[(size_t)n * DIM_ID + lane];
    out[(size_t)n * DIM_ID + lane] = lrelu(acc);
}

// ---------------- layer 2 pre: h2 = x@W_gcn1 ; xhat2 = lrelu(x@lin_w1+b)+id ----------------
__global__ void __launch_bounds__(256) k_layer2pre(
    const float* __restrict__ x,
    const float* __restrict__ Wg, const float* __restrict__ Wl,
    const float* __restrict__ lb, const float* __restrict__ idemb,
    float* __restrict__ h, float* __restrict__ xhat)
{
    const int wave = threadIdx.x >> 6;
    const int lane = threadIdx.x & 63;
    const int n = blockIdx.x * 4 + wave;

    float xv = x[(size_t)n * DIM_ID + lane];
    float a0 = 0.0f, a1 = 0.0f;
    #pragma unroll
    for (int k = 0; k < DIM_ID; ++k) {
        float xk = __shfl(xv, k);
        a0 += xk * Wg[k * DIM_ID + lane];
        a1 += xk * Wl[k * DIM_ID + lane];
    }
    h[(size_t)n * DIM_ID + lane] = a0;
    float xh = lrelu(a1 + lb[lane]);
    xhat[(size_t)n * DIM_ID + lane] = xh + idemb[(size_t)n * DIM_ID + lane];
}

extern "C" void kernel_launch(void* const* d_in, const int* in_sizes, int n_in,
                              void* d_out, int out_size, void* d_ws, size_t ws_size,
                              hipStream_t stream)
{
    const float* features = (const float*)d_in[0];
    const float* idemb    = (const float*)d_in[1];
    const float* pref     = (const float*)d_in[2];
    const float* Wg0      = (const float*)d_in[3];
    const float* Wg1      = (const float*)d_in[4];
    const float* lw0      = (const float*)d_in[5];
    const float* lb0      = (const float*)d_in[6];
    const float* lw1      = (const float*)d_in[7];
    const float* lb1      = (const float*)d_in[8];
    const float* gw0      = (const float*)d_in[9];
    const float* gb0      = (const float*)d_in[10];
    const float* gw1      = (const float*)d_in[11];
    const float* gb1      = (const float*)d_in[12];
    const int*   edges    = (const int*)d_in[13];
    const int*   row      = edges;
    const int*   col      = edges + NUM_EDGES;

    const size_t N64 = (size_t)NUM_NODES * DIM_ID;   // 6.4M floats

    float* deg   = (float*)d_ws;          // NUM_NODES floats
    float* norm  = deg + 131072;          // NUM_EDGES floats
    float* slotA = norm + NUM_EDGES;      // h / h2
    float* slotB = slotA + N64;           // xhat / xhat2
    float* slotC = slotB + N64;           // H / H2
    float* out   = (float*)d_out;         // x1 intermediate, then final output

    // ---- degree + norm ----
    hipMemsetAsync(deg, 0, NUM_NODES * sizeof(float), stream);
    k_deg<<<(NUM_EDGES + 255) / 256, 256, 0, stream>>>(row, deg);
    k_norm<<<(NUM_EDGES + 255) / 256, 256, 0, stream>>>(row, col, deg, norm);

    const int rowBlocks = NUM_NODES / 4;  // 25000

    // ---- layer 1 ----
    k_layer1<<<rowBlocks, 256, 0, stream>>>(pref, features, Wg0, lw0, lb0, idemb,
                                            slotA, slotB);
    hipMemsetAsync(slotC, 0, N64 * sizeof(float), stream);
    k_scatter<<<4096, 256, 0, stream>>>(slotA, norm, row, col, slotC);
    k_combine<<<rowBlocks, 256, 0, stream>>>(slotC, slotB, gw0, gb0, out);

    // ---- layer 2 ----
    k_layer2pre<<<rowBlocks, 256, 0, stream>>>(out, Wg1, lw1, lb1, idemb,
                                               slotA, slotB);
    hipMemsetAsync(slotC, 0, N64 * sizeof(float), stream);
    k_scatter<<<4096, 256, 0, stream>>>(slotA, norm, row, col, slotC);
    k_combine<<<rowBlocks, 256, 0, stream>>>(slotC, slotB, gw1, gb1, out);
}

// Round 2
// 726.974 us; speedup vs baseline: 2.1800x; 2.1800x over previous
//
#include <hip/hip_runtime.h>
#include <hip/hip_bf16.h>

#define NUM_USER   50000
#define NUM_ITEM   50000
#define NUM_NODES  100000
#define DIM_LATENT 256
#define DIM_ID     64
#define NUM_EDGES  2000000

static __device__ __forceinline__ float lrelu(float x) {
    return x > 0.0f ? x : 0.01f * x;
}

// ---------------- edge counting (int) ----------------
__global__ void k_count(const int* __restrict__ row, int* __restrict__ cnt) {
    int t = blockIdx.x * blockDim.x + threadIdx.x;
    if (t < NUM_EDGES) atomicAdd(&cnt[row[t]], 1);
}

// ---------------- exclusive scan over cnt (3 kernels) ----------------
__global__ void __launch_bounds__(256) k_scanA(const int* __restrict__ cnt,
                                               int* __restrict__ offs,
                                               int* __restrict__ bsum) {
    __shared__ int wsum[4];
    int t = threadIdx.x, b = blockIdx.x;
    int idx = b * 256 + t;
    int lane = t & 63, w = t >> 6;
    int c = (idx < NUM_NODES) ? cnt[idx] : 0;
    int v = c;
    #pragma unroll
    for (int off = 1; off < 64; off <<= 1) {
        int u = __shfl_up(v, off);
        if (lane >= off) v += u;
    }
    if (lane == 63) wsum[w] = v;
    __syncthreads();
    int add = 0;
    #pragma unroll
    for (int i = 0; i < 4; ++i) if (i < w) add += wsum[i];
    int incl = v + add;
    if (idx < NUM_NODES) offs[idx] = incl - c;   // exclusive within block
    if (t == 255) bsum[b] = incl;                // block total
}

#define SCAN_BLOCKS 391   // ceil(100000/256)

__global__ void __launch_bounds__(512) k_scanB(const int* __restrict__ bsum,
                                               int* __restrict__ boff) {
    __shared__ int wsum[8];
    int t = threadIdx.x;
    int lane = t & 63, w = t >> 6;
    int c = (t < SCAN_BLOCKS) ? bsum[t] : 0;
    int v = c;
    #pragma unroll
    for (int off = 1; off < 64; off <<= 1) {
        int u = __shfl_up(v, off);
        if (lane >= off) v += u;
    }
    if (lane == 63) wsum[w] = v;
    __syncthreads();
    int add = 0;
    #pragma unroll
    for (int i = 0; i < 8; ++i) if (i < w) add += wsum[i];
    if (t < SCAN_BLOCKS) boff[t] = v + add - c;  // exclusive
}

__global__ void __launch_bounds__(256) k_scanC(const int* __restrict__ cnt,
                                               int* __restrict__ offs,
                                               const int* __restrict__ boff,
                                               int* __restrict__ cursor,
                                               float* __restrict__ dis) {
    int idx = blockIdx.x * 256 + threadIdx.x;
    if (idx < NUM_NODES) {
        int o = offs[idx] + boff[blockIdx.x];
        offs[idx]   = o;
        cursor[idx] = o;
        dis[idx] = rsqrtf((float)max(cnt[idx], 1));
    }
}

// ---------------- bucket edges into CSR order ----------------
__global__ void k_bucket(const int* __restrict__ row, const int* __restrict__ col,
                         int* __restrict__ cursor, int* __restrict__ ecol) {
    int t = blockIdx.x * blockDim.x + threadIdx.x;
    if (t < NUM_EDGES) {
        int r = row[t];
        int pos = atomicAdd(&cursor[r], 1);
        ecol[pos] = col[t];
    }
}

// ---------------- layer 1: normalize rows; h1 = xn@Wg0 ; xhat1 = lrelu(xn@lw0+b0)+id ----------------
// 256 threads = 4 waves, 8 rows/wave, 32 rows/block; 3125 blocks
__global__ void __launch_bounds__(256) k_layer1(
    const float* __restrict__ pref, const float* __restrict__ feat,
    const float* __restrict__ Wg,   const float* __restrict__ Wl,
    const float* __restrict__ lb,   const float* __restrict__ idemb,
    float* __restrict__ h, float* __restrict__ xhat)
{
    __shared__ float xs[32][DIM_LATENT];   // 32 KB
    const int w = threadIdx.x >> 6;
    const int lane = threadIdx.x & 63;
    const int rowBase = blockIdx.x * 32;
    const int lrb = w * 8;

    #pragma unroll
    for (int r = 0; r < 8; ++r) {
        int n = rowBase + lrb + r;
        const float* src = (n < NUM_USER) ? (pref + (size_t)n * DIM_LATENT)
                                          : (feat + (size_t)(n - NUM_USER) * DIM_LATENT);
        float4 v = reinterpret_cast<const float4*>(src)[lane];
        float ss = v.x*v.x + v.y*v.y + v.z*v.z + v.w*v.w;
        #pragma unroll
        for (int off = 32; off >= 1; off >>= 1) ss += __shfl_xor(ss, off);
        float sc = 1.0f / fmaxf(sqrtf(ss), 1e-12f);
        float4 o; o.x = v.x*sc; o.y = v.y*sc; o.z = v.z*sc; o.w = v.w*sc;
        reinterpret_cast<float4*>(xs[lrb + r])[lane] = o;
    }
    __syncthreads();

    float a0[8] = {0,0,0,0,0,0,0,0};
    float a1[8] = {0,0,0,0,0,0,0,0};
    for (int k = 0; k < DIM_LATENT; k += 4) {
        float wg0 = Wg[(k+0)*DIM_ID + lane];
        float wg1 = Wg[(k+1)*DIM_ID + lane];
        float wg2 = Wg[(k+2)*DIM_ID + lane];
        float wg3 = Wg[(k+3)*DIM_ID + lane];
        float wl0 = Wl[(k+0)*DIM_ID + lane];
        float wl1 = Wl[(k+1)*DIM_ID + lane];
        float wl2 = Wl[(k+2)*DIM_ID + lane];
        float wl3 = Wl[(k+3)*DIM_ID + lane];
        #pragma unroll
        for (int r = 0; r < 8; ++r) {
            float4 x4 = *reinterpret_cast<const float4*>(&xs[lrb + r][k]);
            a0[r] += x4.x*wg0 + x4.y*wg1 + x4.z*wg2 + x4.w*wg3;
            a1[r] += x4.x*wl0 + x4.y*wl1 + x4.z*wl2 + x4.w*wl3;
        }
    }
    float lbl = lb[lane];
    #pragma unroll
    for (int r = 0; r < 8; ++r) {
        size_t n = rowBase + lrb + r;
        h[n * DIM_ID + lane] = a0[r];
        xhat[n * DIM_ID + lane] = lrelu(a1[r] + lbl) + idemb[n * DIM_ID + lane];
    }
}

// ---------------- gather: H[n] = dis[n] * sum_e dis[c]*h[c][lane] ----------------
// one wave per node, 4 nodes per block
__global__ void __launch_bounds__(256) k_gather(
    const float* __restrict__ h, const float* __restrict__ dis,
    const int* __restrict__ offs, const int* __restrict__ cnt,
    const int* __restrict__ ecol, float* __restrict__ H)
{
    const int w = threadIdx.x >> 6;
    const int lane = threadIdx.x & 63;
    const int n = blockIdx.x * 4 + w;

    int start = offs[n];
    int m = cnt[n];
    float acc = 0.0f;
    for (int base = 0; base < m; base += 64) {
        int e = base + lane;
        int ec = (e < m) ? ecol[start + e] : 0;
        int lim = min(64, m - base);
        for (int j = 0; j < lim; ++j) {
            int c = __shfl(ec, j);
            acc += dis[c] * h[(size_t)c * DIM_ID + lane];
        }
    }
    H[(size_t)n * DIM_ID + lane] = dis[n] * acc;
}

// ---------------- mid: x1 = lrelu(lrelu(H)@gw0+gb0+xhat1); h2 = x1@Wg1; xhat2 = lrelu(x1@lw1+b1)+id ----------------
__global__ void __launch_bounds__(256) k_mid(
    const float* __restrict__ H, const float* __restrict__ xhat1,
    const float* __restrict__ gw, const float* __restrict__ gb,
    const float* __restrict__ Wg1, const float* __restrict__ lw1,
    const float* __restrict__ lb1, const float* __restrict__ idemb,
    float* __restrict__ h2, float* __restrict__ xhat2)
{
    __shared__ float hs[32][DIM_ID];   // lrelu(H) tile, 8 KB
    __shared__ float x1[32][DIM_ID];   // 8 KB
    const int t = threadIdx.x;
    const int w = t >> 6;
    const int lane = t & 63;
    const int rowBase = blockIdx.x * 32;
    const int lrb = w * 8;

    for (int i = t; i < 32 * DIM_ID; i += 256) {
        int r = i >> 6, d = i & 63;
        hs[r][d] = lrelu(H[(size_t)(rowBase + r) * DIM_ID + d]);
    }
    __syncthreads();

    {
        float acc[8] = {0,0,0,0,0,0,0,0};
        for (int k = 0; k < DIM_ID; k += 4) {
            float g0 = gw[(k+0)*DIM_ID + lane];
            float g1 = gw[(k+1)*DIM_ID + lane];
            float g2 = gw[(k+2)*DIM_ID + lane];
            float g3 = gw[(k+3)*DIM_ID + lane];
            #pragma unroll
            for (int r = 0; r < 8; ++r) {
                float4 hv = *reinterpret_cast<const float4*>(&hs[lrb + r][k]);
                acc[r] += hv.x*g0 + hv.y*g1 + hv.z*g2 + hv.w*g3;
            }
        }
        float gbl = gb[lane];
        #pragma unroll
        for (int r = 0; r < 8; ++r) {
            size_t n = rowBase + lrb + r;
            x1[lrb + r][lane] = lrelu(acc[r] + gbl + xhat1[n * DIM_ID + lane]);
        }
    }
    __syncthreads();

    float a0[8] = {0,0,0,0,0,0,0,0};
    float a1[8] = {0,0,0,0,0,0,0,0};
    for (int k = 0; k < DIM_ID; k += 4) {
        float wg0 = Wg1[(k+0)*DIM_ID + lane];
        float wg1 = Wg1[(k+1)*DIM_ID + lane];
        float wg2 = Wg1[(k+2)*DIM_ID + lane];
        float wg3 = Wg1[(k+3)*DIM_ID + lane];
        float wl0 = lw1[(k+0)*DIM_ID + lane];
        float wl1 = lw1[(k+1)*DIM_ID + lane];
        float wl2 = lw1[(k+2)*DIM_ID + lane];
        float wl3 = lw1[(k+3)*DIM_ID + lane];
        #pragma unroll
        for (int r = 0; r < 8; ++r) {
            float4 x4 = *reinterpret_cast<const float4*>(&x1[lrb + r][k]);
            a0[r] += x4.x*wg0 + x4.y*wg1 + x4.z*wg2 + x4.w*wg3;
            a1[r] += x4.x*wl0 + x4.y*wl1 + x4.z*wl2 + x4.w*wl3;
        }
    }
    float lbl = lb1[lane];
    #pragma unroll
    for (int r = 0; r < 8; ++r) {
        size_t n = rowBase + lrb + r;
        h2[n * DIM_ID + lane] = a0[r];
        xhat2[n * DIM_ID + lane] = lrelu(a1[r] + lbl) + idemb[n * DIM_ID + lane];
    }
}

// ---------------- final: out = lrelu(lrelu(H2)@gw1 + gb1 + xhat2) ----------------
__global__ void __launch_bounds__(256) k_final(
    const float* __restrict__ H, const float* __restrict__ xhat,
    const float* __restrict__ gw, const float* __restrict__ gb,
    float* __restrict__ out)
{
    __shared__ float hs[32][DIM_ID];
    const int t = threadIdx.x;
    const int w = t >> 6;
    const int lane = t & 63;
    const int rowBase = blockIdx.x * 32;
    const int lrb = w * 8;

    for (int i = t; i < 32 * DIM_ID; i += 256) {
        int r = i >> 6, d = i & 63;
        hs[r][d] = lrelu(H[(size_t)(rowBase + r) * DIM_ID + d]);
    }
    __syncthreads();

    float acc[8] = {0,0,0,0,0,0,0,0};
    for (int k = 0; k < DIM_ID; k += 4) {
        float g0 = gw[(k+0)*DIM_ID + lane];
        float g1 = gw[(k+1)*DIM_ID + lane];
        float g2 = gw[(k+2)*DIM_ID + lane];
        float g3 = gw[(k+3)*DIM_ID + lane];
        #pragma unroll
        for (int r = 0; r < 8; ++r) {
            float4 hv = *reinterpret_cast<const float4*>(&hs[lrb + r][k]);
            acc[r] += hv.x*g0 + hv.y*g1 + hv.z*g2 + hv.w*g3;
        }
    }
    float gbl = gb[lane];
    #pragma unroll
    for (int r = 0; r < 8; ++r) {
        size_t n = rowBase + lrb + r;
        out[n * DIM_ID + lane] = lrelu(acc[r] + gbl + xhat[n * DIM_ID + lane]);
    }
}

extern "C" void kernel_launch(void* const* d_in, const int* in_sizes, int n_in,
                              void* d_out, int out_size, void* d_ws, size_t ws_size,
                              hipStream_t stream)
{
    const float* features = (const float*)d_in[0];
    const float* idemb    = (const float*)d_in[1];
    const float* pref     = (const float*)d_in[2];
    const float* Wg0      = (const float*)d_in[3];
    const float* Wg1      = (const float*)d_in[4];
    const float* lw0      = (const float*)d_in[5];
    const float* lb0      = (const float*)d_in[6];
    const float* lw1      = (const float*)d_in[7];
    const float* lb1      = (const float*)d_in[8];
    const float* gw0      = (const float*)d_in[9];
    const float* gb0      = (const float*)d_in[10];
    const float* gw1      = (const float*)d_in[11];
    const float* gb1      = (const float*)d_in[12];
    const int*   edges    = (const int*)d_in[13];
    const int*   row      = edges;
    const int*   col      = edges + NUM_EDGES;

    const size_t N64 = (size_t)NUM_NODES * DIM_ID;   // 6.4M

    int*   cnt    = (int*)d_ws;            // 131072
    int*   offs   = cnt + 131072;          // 131072
    int*   cursor = offs + 131072;         // 131072
    int*   bsum   = cursor + 131072;       // 512
    int*   boff   = bsum + 512;            // 512
    float* dis    = (float*)(boff + 512);  // 131072
    int*   ecol   = (int*)(dis + 131072);  // 2M (pad to 2097152)
    float* slotA  = (float*)(ecol + 2097152); // h1 / h2
    float* slotB  = slotA + N64;              // xhat1 / xhat2
    float* slotC  = slotB + N64;              // H1 / H2
    float* out    = (float*)d_out;

    const int edgeBlocks = (NUM_EDGES + 255) / 256;
    const int rowBlocks32 = NUM_NODES / 32;   // 3125
    const int gatherBlocks = NUM_NODES / 4;   // 25000

    // ---- CSR build ----
    hipMemsetAsync(cnt, 0, NUM_NODES * sizeof(int), stream);
    k_count<<<edgeBlocks, 256, 0, stream>>>(row, cnt);
    k_scanA<<<SCAN_BLOCKS, 256, 0, stream>>>(cnt, offs, bsum);
    k_scanB<<<1, 512, 0, stream>>>(bsum, boff);
    k_scanC<<<SCAN_BLOCKS, 256, 0, stream>>>(cnt, offs, boff, cursor, dis);
    k_bucket<<<edgeBlocks, 256, 0, stream>>>(row, col, cursor, ecol);

    // ---- layer 1 ----
    k_layer1<<<rowBlocks32, 256, 0, stream>>>(pref, features, Wg0, lw0, lb0, idemb,
                                              slotA, slotB);
    k_gather<<<gatherBlocks, 256, 0, stream>>>(slotA, dis, offs, cnt, ecol, slotC);

    // ---- combine1 + layer2 pre (fused) ----
    k_mid<<<rowBlocks32, 256, 0, stream>>>(slotC, slotB, gw0, gb0, Wg1, lw1, lb1,
                                           idemb, slotA, slotB);

    // ---- layer 2 aggregate + final combine ----
    k_gather<<<gatherBlocks, 256, 0, stream>>>(slotA, dis, offs, cnt, ecol, slotC);
    k_final<<<rowBlocks32, 256, 0, stream>>>(slotC, slotB, gw1, gb1, out);
}

// Round 3
// 517.706 us; speedup vs baseline: 3.0612x; 1.4042x over previous
//
#include <hip/hip_runtime.h>

#define NUM_USER   50000
#define NUM_ITEM   50000
#define NUM_NODES  100000
#define DIM_LATENT 256
#define DIM_ID     64
#define NUM_EDGES  2000000

typedef __attribute__((ext_vector_type(8))) short bf8_t;
typedef __attribute__((ext_vector_type(4))) float f4_t;

static __device__ __forceinline__ float lrelu(float x) {
    return x > 0.0f ? x : 0.01f * x;
}
static __device__ __forceinline__ unsigned short f2bf(float f) {
    unsigned u = __float_as_uint(f);
    u += 0x7fff + ((u >> 16) & 1);
    return (unsigned short)(u >> 16);
}

// ---------------- edge counting ----------------
__global__ void k_count(const int* __restrict__ row, int* __restrict__ cnt) {
    int t = blockIdx.x * blockDim.x + threadIdx.x;
    if (t < NUM_EDGES) atomicAdd(&cnt[row[t]], 1);
}

// ---------------- exclusive scan (3 kernels) ----------------
__global__ void __launch_bounds__(256) k_scanA(const int* __restrict__ cnt,
                                               int* __restrict__ offs,
                                               int* __restrict__ bsum) {
    __shared__ int wsum[4];
    int t = threadIdx.x, b = blockIdx.x;
    int idx = b * 256 + t;
    int lane = t & 63, w = t >> 6;
    int c = (idx < NUM_NODES) ? cnt[idx] : 0;
    int v = c;
    #pragma unroll
    for (int off = 1; off < 64; off <<= 1) {
        int u = __shfl_up(v, off);
        if (lane >= off) v += u;
    }
    if (lane == 63) wsum[w] = v;
    __syncthreads();
    int add = 0;
    #pragma unroll
    for (int i = 0; i < 4; ++i) if (i < w) add += wsum[i];
    int incl = v + add;
    if (idx < NUM_NODES) offs[idx] = incl - c;
    if (t == 255) bsum[b] = incl;
}

#define SCAN_BLOCKS 391

__global__ void __launch_bounds__(512) k_scanB(const int* __restrict__ bsum,
                                               int* __restrict__ boff) {
    __shared__ int wsum[8];
    int t = threadIdx.x;
    int lane = t & 63, w = t >> 6;
    int c = (t < SCAN_BLOCKS) ? bsum[t] : 0;
    int v = c;
    #pragma unroll
    for (int off = 1; off < 64; off <<= 1) {
        int u = __shfl_up(v, off);
        if (lane >= off) v += u;
    }
    if (lane == 63) wsum[w] = v;
    __syncthreads();
    int add = 0;
    #pragma unroll
    for (int i = 0; i < 8; ++i) if (i < w) add += wsum[i];
    if (t < SCAN_BLOCKS) boff[t] = v + add - c;
}

__global__ void __launch_bounds__(256) k_scanC(const int* __restrict__ cnt,
                                               int* __restrict__ offs,
                                               const int* __restrict__ boff,
                                               int* __restrict__ cursor,
                                               float* __restrict__ dis) {
    int idx = blockIdx.x * 256 + threadIdx.x;
    if (idx < NUM_NODES) {
        int o = offs[idx] + boff[blockIdx.x];
        offs[idx]   = o;
        cursor[idx] = o;
        dis[idx] = rsqrtf((float)max(cnt[idx], 1));
    }
}

// ---------------- bucket edges into CSR order ----------------
__global__ void k_bucket(const int* __restrict__ row, const int* __restrict__ col,
                         int* __restrict__ cursor, int* __restrict__ ecol) {
    int t = blockIdx.x * blockDim.x + threadIdx.x;
    if (t < NUM_EDGES) {
        int r = row[t];
        int pos = atomicAdd(&cursor[r], 1);
        ecol[pos] = col[t];
    }
}

// ---------------- weight prep: Wg0,lw0 -> bf16 fragment-order table ----------------
// frag layout: index = ((ks*8 + t)*64 + lane), 8 bf16 each;
// value[e] = W[ks*32 + (lane>>4)*8 + e][ t<4 ? t*16+(lane&15) : (t-4)*16+(lane&15) ]
__global__ void __launch_bounds__(256) k_wprep(const float* __restrict__ Wg,
                                               const float* __restrict__ Wl,
                                               unsigned short* __restrict__ wfrag) {
    int g = blockIdx.x * 256 + threadIdx.x;     // 4096 total
    if (g >= 4096) return;
    int ks = g >> 9;
    int t  = (g >> 6) & 7;
    int l  = g & 63;
    const float* W = (t < 4) ? Wg : Wl;
    int colg = (t & 3) * 16 + (l & 15);
    int kb = ks * 32 + (l >> 4) * 8;
    unsigned short o[8];
    #pragma unroll
    for (int e = 0; e < 8; ++e) o[e] = f2bf(W[(size_t)(kb + e) * DIM_ID + colg]);
    unsigned short* dst = wfrag + (size_t)g * 8;
    #pragma unroll
    for (int e = 0; e < 8; ++e) dst[e] = o[e];
}

// ---------------- layer 1 (MFMA): normalize rows; hbf = bf16(dis*(xn@Wg0));
//                  xhat = lrelu(xn@lw0+b0)+id ----------------
// 256 threads = 4 waves, 64 rows/block, 1563 blocks (last block tail-guarded)
__global__ void __launch_bounds__(256) k_l1(
    const float* __restrict__ pref, const float* __restrict__ feat,
    const unsigned short* __restrict__ wfrag,
    const float* __restrict__ lb,   const float* __restrict__ idemb,
    const float* __restrict__ dis,
    unsigned short* __restrict__ hbf, float* __restrict__ xhat)
{
    __shared__ unsigned short xs[64][264];   // bf16, padded stride 528B
    const int w = threadIdx.x >> 6;
    const int lane = threadIdx.x & 63;
    const int ql = lane & 15, q = lane >> 4;
    const int rowBase = blockIdx.x * 64;

    // phase 1: normalize 16 rows per wave, write bf16 to LDS
    for (int r = 0; r < 16; ++r) {
        int n = rowBase + w * 16 + r;
        float4 v = make_float4(0.f, 0.f, 0.f, 0.f);
        if (n < NUM_NODES) {
            const float* src = (n < NUM_USER) ? (pref + (size_t)n * DIM_LATENT)
                                              : (feat + (size_t)(n - NUM_USER) * DIM_LATENT);
            v = reinterpret_cast<const float4*>(src)[lane];
        }
        float ss = v.x*v.x + v.y*v.y + v.z*v.z + v.w*v.w;
        #pragma unroll
        for (int off = 32; off >= 1; off >>= 1) ss += __shfl_xor(ss, off);
        float sc = 1.0f / fmaxf(sqrtf(ss), 1e-12f);
        ushort4 p;
        p.x = f2bf(v.x * sc); p.y = f2bf(v.y * sc);
        p.z = f2bf(v.z * sc); p.w = f2bf(v.w * sc);
        *reinterpret_cast<ushort4*>(&xs[w * 16 + r][lane * 4]) = p;
    }
    __syncthreads();

    // phase 2: 8 K-steps x 8 N-tiles of mfma 16x16x32
    f4_t acc[8];
    #pragma unroll
    for (int t = 0; t < 8; ++t) acc[t] = (f4_t){0.f, 0.f, 0.f, 0.f};

    const bf8_t* wf = reinterpret_cast<const bf8_t*>(wfrag);
    #pragma unroll 2
    for (int ks = 0; ks < 8; ++ks) {
        bf8_t a = *reinterpret_cast<const bf8_t*>(&xs[w * 16 + ql][ks * 32 + q * 8]);
        #pragma unroll
        for (int t = 0; t < 8; ++t) {
            bf8_t b = wf[(ks * 8 + t) * 64 + lane];
            acc[t] = __builtin_amdgcn_mfma_f32_16x16x32_bf16(a, b, acc[t], 0, 0, 0);
        }
    }

    // epilogue
    int nn[4];
    float dn[4];
    #pragma unroll
    for (int reg = 0; reg < 4; ++reg) {
        nn[reg] = rowBase + w * 16 + q * 4 + reg;
        dn[reg] = (nn[reg] < NUM_NODES) ? dis[nn[reg]] : 0.0f;
    }
    #pragma unroll
    for (int t = 0; t < 4; ++t) {
        int colg = t * 16 + ql;
        #pragma unroll
        for (int reg = 0; reg < 4; ++reg)
            if (nn[reg] < NUM_NODES)
                hbf[(size_t)nn[reg] * DIM_ID + colg] = f2bf(acc[t][reg] * dn[reg]);
    }
    #pragma unroll
    for (int t = 4; t < 8; ++t) {
        int colg = (t - 4) * 16 + ql;
        float lbl = lb[colg];
        #pragma unroll
        for (int reg = 0; reg < 4; ++reg)
            if (nn[reg] < NUM_NODES) {
                size_t o = (size_t)nn[reg] * DIM_ID + colg;
                xhat[o] = lrelu(acc[t][reg] + lbl) + idemb[o];
            }
    }
}

// ---------------- gather: H[n] = dis[n] * sum_e hbf[ecol[e]]  (hbf pre-scaled) ----------------
// one wave per node; 4 edges per iteration (quarter-wave per edge, 4 dims/lane)
__global__ void __launch_bounds__(256) k_gather(
    const unsigned short* __restrict__ hbf, const float* __restrict__ dis,
    const int* __restrict__ offs, const int* __restrict__ cnt,
    const int* __restrict__ ecol, float* __restrict__ H)
{
    const int w = threadIdx.x >> 6;
    const int lane = threadIdx.x & 63;
    const int ql = lane & 15, q = lane >> 4;
    const int n = blockIdx.x * 4 + w;

    int start = offs[n];
    int m = cnt[n];
    float a0 = 0.f, a1 = 0.f, a2 = 0.f, a3 = 0.f;

    for (int base = 0; base < m; base += 64) {
        int e = base + lane;
        int ec = (e < m) ? ecol[start + e] : 0;
        int lim = m - base; if (lim > 64) lim = 64;
        int nj = (lim + 3) >> 2;
        for (int j = 0; j < nj; ++j) {
            int idx = j * 4 + q;
            int c = __shfl(ec, idx);
            if (idx < lim) {
                uint2 u = *reinterpret_cast<const uint2*>(&hbf[(size_t)c * DIM_ID + ql * 4]);
                a0 += __uint_as_float(u.x << 16);
                a1 += __uint_as_float(u.x & 0xffff0000u);
                a2 += __uint_as_float(u.y << 16);
                a3 += __uint_as_float(u.y & 0xffff0000u);
            }
        }
    }
    #pragma unroll
    for (int off = 16; off <= 32; off <<= 1) {
        a0 += __shfl_xor(a0, off);
        a1 += __shfl_xor(a1, off);
        a2 += __shfl_xor(a2, off);
        a3 += __shfl_xor(a3, off);
    }
    if (lane < 16) {
        float dn = dis[n];
        float4 o = make_float4(a0 * dn, a1 * dn, a2 * dn, a3 * dn);
        *reinterpret_cast<float4*>(&H[(size_t)n * DIM_ID + lane * 4]) = o;
    }
}

// ---------------- mid: x1 = lrelu(lrelu(H)@gw0+gb0+xhat1);
//                  hbf = bf16(dis*(x1@Wg1)); xhat2 = lrelu(x1@lw1+b1)+id ----------------
__global__ void __launch_bounds__(256) k_mid(
    const float* __restrict__ H, const float* __restrict__ xhat1,
    const float* __restrict__ gw, const float* __restrict__ gb,
    const float* __restrict__ Wg1, const float* __restrict__ lw1,
    const float* __restrict__ lb1, const float* __restrict__ idemb,
    const float* __restrict__ dis,
    unsigned short* __restrict__ hbf, float* __restrict__ xhat2)
{
    __shared__ float hs[32][DIM_ID];
    __shared__ float x1[32][DIM_ID];
    const int t = threadIdx.x;
    const int w = t >> 6;
    const int lane = t & 63;
    const int rowBase = blockIdx.x * 32;
    const int lrb = w * 8;

    for (int i = t; i < 32 * DIM_ID; i += 256) {
        int r = i >> 6, d = i & 63;
        hs[r][d] = lrelu(H[(size_t)(rowBase + r) * DIM_ID + d]);
    }
    __syncthreads();

    {
        float acc[8] = {0,0,0,0,0,0,0,0};
        for (int k = 0; k < DIM_ID; k += 4) {
            float g0 = gw[(k+0)*DIM_ID + lane];
            float g1 = gw[(k+1)*DIM_ID + lane];
            float g2 = gw[(k+2)*DIM_ID + lane];
            float g3 = gw[(k+3)*DIM_ID + lane];
            #pragma unroll
            for (int r = 0; r < 8; ++r) {
                float4 hv = *reinterpret_cast<const float4*>(&hs[lrb + r][k]);
                acc[r] += hv.x*g0 + hv.y*g1 + hv.z*g2 + hv.w*g3;
            }
        }
        float gbl = gb[lane];
        #pragma unroll
        for (int r = 0; r < 8; ++r) {
            size_t n = rowBase + lrb + r;
            x1[lrb + r][lane] = lrelu(acc[r] + gbl + xhat1[n * DIM_ID + lane]);
        }
    }
    __syncthreads();

    float a0[8] = {0,0,0,0,0,0,0,0};
    float a1[8] = {0,0,0,0,0,0,0,0};
    for (int k = 0; k < DIM_ID; k += 4) {
        float wg0 = Wg1[(k+0)*DIM_ID + lane];
        float wg1 = Wg1[(k+1)*DIM_ID + lane];
        float wg2 = Wg1[(k+2)*DIM_ID + lane];
        float wg3 = Wg1[(k+3)*DIM_ID + lane];
        float wl0 = lw1[(k+0)*DIM_ID + lane];
        float wl1 = lw1[(k+1)*DIM_ID + lane];
        float wl2 = lw1[(k+2)*DIM_ID + lane];
        float wl3 = lw1[(k+3)*DIM_ID + lane];
        #pragma unroll
        for (int r = 0; r < 8; ++r) {
            float4 x4 = *reinterpret_cast<const float4*>(&x1[lrb + r][k]);
            a0[r] += x4.x*wg0 + x4.y*wg1 + x4.z*wg2 + x4.w*wg3;
            a1[r] += x4.x*wl0 + x4.y*wl1 + x4.z*wl2 + x4.w*wl3;
        }
    }
    float lbl = lb1[lane];
    #pragma unroll
    for (int r = 0; r < 8; ++r) {
        size_t n = rowBase + lrb + r;
        float dn = dis[n];
        hbf[n * DIM_ID + lane] = f2bf(a0[r] * dn);
        xhat2[n * DIM_ID + lane] = lrelu(a1[r] + lbl) + idemb[n * DIM_ID + lane];
    }
}

// ---------------- final: out = lrelu(lrelu(H2)@gw1 + gb1 + xhat2) ----------------
__global__ void __launch_bounds__(256) k_final(
    const float* __restrict__ H, const float* __restrict__ xhat,
    const float* __restrict__ gw, const float* __restrict__ gb,
    float* __restrict__ out)
{
    __shared__ float hs[32][DIM_ID];
    const int t = threadIdx.x;
    const int w = t >> 6;
    const int lane = t & 63;
    const int rowBase = blockIdx.x * 32;
    const int lrb = w * 8;

    for (int i = t; i < 32 * DIM_ID; i += 256) {
        int r = i >> 6, d = i & 63;
        hs[r][d] = lrelu(H[(size_t)(rowBase + r) * DIM_ID + d]);
    }
    __syncthreads();

    float acc[8] = {0,0,0,0,0,0,0,0};
    for (int k = 0; k < DIM_ID; k += 4) {
        float g0 = gw[(k+0)*DIM_ID + lane];
        float g1 = gw[(k+1)*DIM_ID + lane];
        float g2 = gw[(k+2)*DIM_ID + lane];
        float g3 = gw[(k+3)*DIM_ID + lane];
        #pragma unroll
        for (int r = 0; r < 8; ++r) {
            float4 hv = *reinterpret_cast<const float4*>(&hs[lrb + r][k]);
            acc[r] += hv.x*g0 + hv.y*g1 + hv.z*g2 + hv.w*g3;
        }
    }
    float gbl = gb[lane];
    #pragma unroll
    for (int r = 0; r < 8; ++r) {
        size_t n = rowBase + lrb + r;
        out[n * DIM_ID + lane] = lrelu(acc[r] + gbl + xhat[n * DIM_ID + lane]);
    }
}

extern "C" void kernel_launch(void* const* d_in, const int* in_sizes, int n_in,
                              void* d_out, int out_size, void* d_ws, size_t ws_size,
                              hipStream_t stream)
{
    const float* features = (const float*)d_in[0];
    const float* idemb    = (const float*)d_in[1];
    const float* pref     = (const float*)d_in[2];
    const float* Wg0      = (const float*)d_in[3];
    const float* Wg1      = (const float*)d_in[4];
    const float* lw0      = (const float*)d_in[5];
    const float* lb0      = (const float*)d_in[6];
    const float* lw1      = (const float*)d_in[7];
    const float* lb1      = (const float*)d_in[8];
    const float* gw0      = (const float*)d_in[9];
    const float* gb0      = (const float*)d_in[10];
    const float* gw1      = (const float*)d_in[11];
    const float* gb1      = (const float*)d_in[12];
    const int*   edges    = (const int*)d_in[13];
    const int*   row      = edges;
    const int*   col      = edges + NUM_EDGES;

    char* ws = (char*)d_ws;
    int*   cnt    = (int*)(ws + 0);
    int*   offs   = (int*)(ws + 524288);
    int*   cursor = (int*)(ws + 1048576);
    int*   bsum   = (int*)(ws + 1572864);
    int*   boff   = (int*)(ws + 1576960);
    float* dis    = (float*)(ws + 1581056);
    int*   ecol   = (int*)(ws + 2105344);
    unsigned short* wfrag = (unsigned short*)(ws + 10493952);   // 64 KB
    unsigned short* hbf   = (unsigned short*)(ws + 10559488);   // 12.8 MB
    float* xhat   = (float*)(ws + 23359488);                    // 25.6 MB
    float* Hbuf   = (float*)(ws + 48959488);                    // 25.6 MB
    float* out    = (float*)d_out;

    const int edgeBlocks = (NUM_EDGES + 255) / 256;
    const int l1Blocks = (NUM_NODES + 63) / 64;     // 1563
    const int rowBlocks32 = NUM_NODES / 32;         // 3125
    const int gatherBlocks = NUM_NODES / 4;         // 25000

    // ---- CSR build + weight prep ----
    hipMemsetAsync(cnt, 0, NUM_NODES * sizeof(int), stream);
    k_wprep<<<16, 256, 0, stream>>>(Wg0, lw0, wfrag);
    k_count<<<edgeBlocks, 256, 0, stream>>>(row, cnt);
    k_scanA<<<SCAN_BLOCKS, 256, 0, stream>>>(cnt, offs, bsum);
    k_scanB<<<1, 512, 0, stream>>>(bsum, boff);
    k_scanC<<<SCAN_BLOCKS, 256, 0, stream>>>(cnt, offs, boff, cursor, dis);
    k_bucket<<<edgeBlocks, 256, 0, stream>>>(row, col, cursor, ecol);

    // ---- layer 1 ----
    k_l1<<<l1Blocks, 256, 0, stream>>>(pref, features, wfrag, lb0, idemb, dis,
                                       hbf, xhat);
    k_gather<<<gatherBlocks, 256, 0, stream>>>(hbf, dis, offs, cnt, ecol, Hbuf);

    // ---- combine1 + layer2 pre (fused) ----
    k_mid<<<rowBlocks32, 256, 0, stream>>>(Hbuf, xhat, gw0, gb0, Wg1, lw1, lb1,
                                           idemb, dis, hbf, xhat);

    // ---- layer 2 aggregate + final combine ----
    k_gather<<<gatherBlocks, 256, 0, stream>>>(hbf, dis, offs, cnt, ecol, Hbuf);
    k_final<<<rowBlocks32, 256, 0, stream>>>(Hbuf, xhat, gw1, gb1, out);
}